// Round 8
// baseline (64.230 us; speedup 1.0000x reference)
//
#include <hip/hip_runtime.h>

#define NB     65536
#define NUM_T  200
#define SUB    4          // 4 RK4 substeps per output step (ref: 8; proven)
#define S1     120        // wave-type A: stores steps [0,120)
                          // wave-type B: fast-forwards 120 steps, stores [120,200)

// one RK4 substep on rescaled state (u = beta*S, I); 22 VALU ops
#define SUBSTEP()                                   \
    do {                                            \
        const float t1 = u * I;                     \
        const float u2 = fmaf(-cbA, t1, u);         \
        const float J1 = fmaf(-cgA, I, I);          \
        const float I2 = fmaf(h2, t1, J1);          \
        const float t2 = u2 * I2;                   \
        const float u3 = fmaf(-cbA, t2, u);         \
        const float J2 = fmaf(-cgA, I2, I);         \
        const float I3 = fmaf(h2, t2, J2);          \
        float wb = fmaf(2.0f, t2, t1);              \
        float wI = fmaf(2.0f, I2, I);               \
        const float t3 = u3 * I3;                   \
        const float u4 = fmaf(-cbB, t3, u);         \
        const float J3 = fmaf(-cgB, I3, I);         \
        const float I4 = fmaf(h, t3, J3);           \
        wb = fmaf(2.0f, t3, wb);                    \
        wI = fmaf(2.0f, I3, wI);                    \
        const float t4 = u4 * I4;                   \
        wb += t4;                                   \
        wI += I4;                                   \
        u = fmaf(-cbF, wb, u);                      \
        const float tt = fmaf(-cgF, wI, I);         \
        I = fmaf(h6, wb, tt);                       \
    } while (0)

__global__ __launch_bounds__(256, 1) void sir_rk4_seg_kernel(
    const float4* __restrict__ params, float* __restrict__ out)
{
    const int tid  = threadIdx.x;
    const int blk  = blockIdx.x;
    const int wid  = tid >> 6;          // wave in block: 0..3
    const int lane = tid & 63;
    const int seg  = wid & 1;           // 0: steps [0,S1)   1: steps [S1,NUM_T)
    const int sys  = blk * 128 + (wid >> 1) * 64 + lane;

    const float4 p = params[sys];
    const float beta  = p.x;
    const float gamma = p.y;
    const float S0    = p.z;

    // rescaled state u = beta*S (bSI = u*I in one mul)
    float u = beta * S0;
    float I = p.w;

    const bool  bpos  = (beta > 0.0f);
    const float rbeta = bpos ? (1.0f / beta) : 0.0f;

    // constant dt = fp32 linspace step (proven R5-R7: absmax identical)
    const float step = 100.0f / 199.0f;
    const float h  = step * (1.0f / SUB);
    const float h2 = 0.5f * h;
    const float h6 = h * (1.0f / 6.0f);
    const float cbA = h2 * beta,  cbB = h * beta,  cbF = h6 * beta;
    const float cgA = h2 * gamma, cgB = h * gamma, cgF = h6 * gamma;

    const int tstart = seg ? S1 : 0;
    const int tcount = seg ? (NUM_T - S1) : S1;

    // ---- fast-forward (segment 1 only): y_0 -> y_tstart, no stores ----
    const int ffn = tstart * SUB;       // 480 or 0; wave-uniform
    #pragma unroll 4
    for (int k = 0; k < ffn; ++k) {
        SUBSTEP();
    }

    // ---- store phase: steps [tstart, tstart+tcount), groups of 4 ----
    float* o = out + (size_t)sys * (NUM_T * 3) + tstart * 3;
    for (int g = 0; g < tcount / 4; ++g) {
        float buf[12];
        #pragma unroll
        for (int j = 0; j < 4; ++j) {
            const int lt = g * 4 + j;
            if (lt > 0 || seg) {        // advance except at y_0 (seg0 first step)
                if (lt > 0) {
                    #pragma unroll
                    for (int s = 0; s < SUB; ++s) SUBSTEP();
                }
            }
            const float Sout = bpos ? (u * rbeta) : S0;
            buf[j * 3 + 0] = Sout;
            buf[j * 3 + 1] = I;
            buf[j * 3 + 2] = 1.0f - Sout - I;
        }
        float4* o4 = reinterpret_cast<float4*>(o + g * 12);
        o4[0] = make_float4(buf[0], buf[1], buf[2],  buf[3]);
        o4[1] = make_float4(buf[4], buf[5], buf[6],  buf[7]);
        o4[2] = make_float4(buf[8], buf[9], buf[10], buf[11]);
    }
}

extern "C" void kernel_launch(void* const* d_in, const int* in_sizes, int n_in,
                              void* d_out, int out_size, void* d_ws, size_t ws_size,
                              hipStream_t stream) {
    (void)in_sizes; (void)n_in; (void)out_size; (void)d_ws; (void)ws_size;
    const float4* params = (const float4*)d_in[0];
    float* out = (float*)d_out;
    // 2 threads per system (one per time segment): 131072 threads total
    sir_rk4_seg_kernel<<<(NB * 2) / 256, 256, 0, stream>>>(params, out);
}